// Round 7
// baseline (413.852 us; speedup 1.0000x reference)
//
#include <hip/hip_runtime.h>

// 1D Euler, Roe flux + Harten entropy fix, 32 fused steps. Round 21:
// r20 (243us) regression root cause per counters: per-wave dt polling
// multiplied flag traffic x16 (WRITE 14->35MB, FETCH 6.5->15.5MB,
// busy*dur 86->117us) -- 4096 waves spinning on 1KB of flag lines
// serialized at the coherence point. The structural wins (1 barrier,
// shfl exchange, 1.5KB LDS) are kept; polling reverts to ONE wave.
// Mechanism: dt_k = f(row k-1) (r19 slack semantics, verified) lets the
// poll for step k+1 run DURING step k and cross the EXISTING end-of-step
// barrier: wave0 polls row k mid-step, writes sam[(k+1)&1] pre-barrier;
// at step k all waves read sam[k&1] (one LDS broadcast, parity-race-free,
// slots reused only across 2 barriers). k=0: one-time all-wave poll of
// row 0 (also produces sam[1], since dt_1 = f(row 0) as in r19).
// dt values and reduction tree identical to r19 => identical trajectory.
// Block-to-block protocol (halo rows+flags, sign-SET sentinel, XCD
// swizzle, device scope) byte-for-byte r19/r20.

#define NXC   1048576
#define GAM   1.4f
#define GM1   0.4f
#define IGM1  2.5f
#define CFLC  0.5f
#define DXC   1e-3f
#define IDXC  1000.0f
#define EFIX  0.1f
#define NSTEPS 32
#define NSLOT  (NSTEPS + 1)

#define ABLK  1024
#define ACPT  4
#define ATILE (ABLK*ACPT)      // 4096
#define ANBLK (NXC/ATILE)      // 256 blocks = 1/CU (proven residency)
#define NWAVE (ABLK/64)        // 16

#define CTRL_TOTAL (NSLOT * ANBLK)

__device__ __forceinline__ float frcp(float x){ return __builtin_amdgcn_rcpf(x); }
__device__ __forceinline__ float frsq(float x){ return __builtin_amdgcn_rsqf(x); }
__device__ __forceinline__ float fsqrt_(float x){ return __builtin_amdgcn_sqrtf(x); }

// Device (agent) scope: cross-XCD correct, no system-level overhead.
__device__ __forceinline__ float devloadf(const float* p) {
    return __hip_atomic_load(p, __ATOMIC_RELAXED, __HIP_MEMORY_SCOPE_AGENT);
}
__device__ __forceinline__ void devstoref(float* p, float v) {
    __hip_atomic_store(p, v, __ATOMIC_RELAXED, __HIP_MEMORY_SCOPE_AGENT);
}
__device__ __forceinline__ unsigned devloadu(const unsigned* p) {
    return __hip_atomic_load(p, __ATOMIC_RELAXED, __HIP_MEMORY_SCOPE_AGENT);
}
__device__ __forceinline__ void devstoreu(unsigned* p, unsigned v) {
    __hip_atomic_store(p, v, __ATOMIC_RELAXED, __HIP_MEMORY_SCOPE_AGENT);
}

__device__ __forceinline__ float wave_max(float v) {
    #pragma unroll
    for (int k = 32; k >= 1; k >>= 1)
        v = fmaxf(v, __shfl_xor(v, k));
    return v;
}

// Sign-SET sentinel = "unpublished" (deterministic regardless of ws poison).
__global__ void bmax_init(unsigned* z) {
    int i = blockIdx.x * 256 + threadIdx.x;
    if (i < CTRL_TOTAL) z[i] = 0xAAAAAAAAu;
}

// One Roe flux from scalar L/R states (s = sqrt(rho), g = (E+p)/sqrt(rho)).
__device__ __forceinline__ void roe(
        float rL, float uL, float pL, float sL, float gL,
        float rR, float uR, float pR, float sR, float gR,
        float& Frj, float& Fmj, float& Fej) {
    float invden = frcp(sL + sR);
    float ur = (sL * uL + sR * uR) * invden;
    float Hr = (gL + gR) * invden;
    float c2u = fmaxf(GM1 * (Hr - 0.5f * ur * ur), 1e-10f);
    float qc = frsq(c2u);
    float c  = c2u * qc;             // sqrt(c2u), ~1 ulp vs v_sqrt
    float inv2c2 = 0.5f * qc * qc;   // 1/(2*c2), replaces v_rcp
    float eps = EFIX * c;
    float l1 = ur - c, l3 = ur + c;
    float a1 = fsqrt_(l1 * l1 + eps * eps);
    float a2 = fsqrt_(ur * ur + eps * eps);
    float a3 = fsqrt_(l3 * l3 + eps * eps);
    float drho = rR - rL;
    float du   = uR - uL;
    float dp   = pR - pL;
    float al2 = drho - (dp + dp) * inv2c2;
    float tcd = c * rR * du;
    float al1 = (dp - tcd) * inv2c2;
    float al3 = (dp + tcd) * inv2c2;
    float FrL = rL * uL, FrR = rR * uR;
    float FmL = FrL * uL + pL, FmR = FrR * uR + pR;
    float FeL = uL * (gL * sL), FeR = uR * (gR * sR);
    float w1 = a1 * al1, w2 = a2 * al2, w3 = a3 * al3;
    Frj = 0.5f * (FrL + FrR - (w1 + w2 + w3));
    Fmj = 0.5f * (FmL + FmR - (w1 * l1 + w2 * ur + w3 * l3));
    Fej = 0.5f * (FeL + FeR - (w1 * (Hr - ur * c) + w2 * (0.5f * ur * ur)
                               + w3 * (Hr + ur * c)));
}

__global__ __launch_bounds__(ABLK, 4) void euler_async(
        const float* __restrict__ rho0, const float* __restrict__ u0,
        const float* __restrict__ p0, const float* __restrict__ tf,
        float* __restrict__ out, unsigned* __restrict__ bmax,
        float* __restrict__ halo) {   // halo: NSLOT rows x ANBLK x 6
    // Cross-wave exchange: double-buffered by step parity; writes happen
    // before the (single) end-of-step barrier, reads after it.
    __shared__ float W3[2][NWAVE][5];  // wave w's lane63 cell3 (r,u,p,s,g)
    __shared__ float R0[2][NWAVE][5];  // wave w's lane0  cell0 (r,u,p,s,g)
    __shared__ float red[2][NWAVE];    // per-wave nm
    __shared__ float sam[2];           // global amax, parity-pipelined

    const int tid = threadIdx.x;
    // XCD swizzle (kept from r18: time-neutral, lowers L2 misses).
    const int lb = (blockIdx.x & 7) * (ANBLK / 8) + (blockIdx.x >> 3);
    const int c0 = lb * ATILE + ACPT * tid;
    const int lane = tid & 63, wid = tid >> 6;

    float cr[4], cu[4], cp[4], cE[4], cs[4], cg[4];

    // ---- prepass: inputs -> regs (incl E,s,g); publish halo+bmax row 0 --
    {
        float4 r4 = *(const float4*)(rho0 + c0);
        float4 u4 = *(const float4*)(u0 + c0);
        float4 p4 = *(const float4*)(p0 + c0);
        cr[0]=r4.x; cr[1]=r4.y; cr[2]=r4.z; cr[3]=r4.w;
        cu[0]=u4.x; cu[1]=u4.y; cu[2]=u4.z; cu[3]=u4.w;
        cp[0]=p4.x; cp[1]=p4.y; cp[2]=p4.z; cp[3]=p4.w;
        float nm = 0.f;
        #pragma unroll
        for (int c = 0; c < 4; ++c) {
            float E = cp[c] * IGM1 + 0.5f * cr[c] * cu[c] * cu[c];
            float q = frsq(cr[c]);
            cE[c] = E;
            cs[c] = cr[c] * q;
            cg[c] = (E + cp[c]) * q;
            nm = fmaxf(nm, fabsf(cu[c]) + fsqrt_(GAM * cp[c] * (q * q)));
        }
        if (lane == 63) {
            W3[0][wid][0]=cr[3]; W3[0][wid][1]=cu[3]; W3[0][wid][2]=cp[3];
            W3[0][wid][3]=cs[3]; W3[0][wid][4]=cg[3];
        }
        if (lane == 0) {
            R0[0][wid][0]=cr[0]; R0[0][wid][1]=cu[0]; R0[0][wid][2]=cp[0];
            R0[0][wid][3]=cs[0]; R0[0][wid][4]=cg[0];
        }
        if (tid == 0) {
            float* h = halo + (size_t)lb * 6;
            devstoref(h, cr[0]); devstoref(h+1, cu[0]); devstoref(h+2, cp[0]);
        }
        if (tid == ABLK - 1) {
            float* h = halo + (size_t)lb * 6 + 3;
            devstoref(h, cr[3]); devstoref(h+1, cu[3]); devstoref(h+2, cp[3]);
        }
        nm = wave_max(nm);
        if (lane == 0) red[0][wid] = nm;
        __syncthreads();      // drains halo stores + all LDS buffers (par 0)
        if (wid == 8 && lane < NWAVE) {
            float bm = red[0][lane];
            bm = fmaxf(bm, __shfl_xor(bm, 8));
            bm = fmaxf(bm, __shfl_xor(bm, 4));
            bm = fmaxf(bm, __shfl_xor(bm, 2));
            bm = fmaxf(bm, __shfl_xor(bm, 1));
            if (lane == 0) devstoreu(&bmax[lb], __float_as_uint(bm));
        }
    }
    float t = 0.f;
    const float tfin = *tf;

    for (int k = 0; k < NSTEPS; ++k) {
        const unsigned* brow = bmax + (size_t)k * ANBLK;   // row k flags
        const int kb = k & 1;
        float Fr[5], Fm[5], Fe[5];

        // A1. wave0 only (1<=k<=30): issue poll loads of row k for the
        //     NEXT step's dt (consumed pre-barrier in E). Row k was
        //     published at end of step k-1 -> ~first-try in steady state.
        const bool w0poll = (wid == 0) && (k >= 1) && (k < NSTEPS - 1);
        unsigned pv0 = 0, pv1 = 0, pv2 = 0, pv3 = 0;
        if (w0poll) {
            pv0 = devloadu(&brow[lane]);
            pv1 = devloadu(&brow[64 + lane]);
            pv2 = devloadu(&brow[128 + lane]);
            pv3 = devloadu(&brow[192 + lane]);
        }

        // A2. left boundary state for lane0 of each wave (LDS / halo).
        float wl0, wl1, wl2, wl3, wl4;
        if (lane == 0) {
            if (tid == 0) {
                if (lb > 0) {
                    while (devloadu(&brow[lb - 1]) & 0x80000000u)
                        __builtin_amdgcn_s_sleep(1);
                    const float* h = halo + ((size_t)k * ANBLK + (lb - 1)) * 6 + 3;
                    wl0 = devloadf(h); wl1 = devloadf(h+1); wl2 = devloadf(h+2);
                    float El = wl2 * IGM1 + 0.5f * wl0 * wl1 * wl1;
                    float ql = frsq(wl0);
                    wl3 = wl0 * ql; wl4 = (El + wl2) * ql;
                } else {
                    wl0 = cr[0]; wl1 = cu[0]; wl2 = cp[0];
                    wl3 = cs[0]; wl4 = cg[0];
                }
            } else {
                const float* w = W3[kb][wid - 1];
                wl0 = w[0]; wl1 = w[1]; wl2 = w[2]; wl3 = w[3]; wl4 = w[4];
            }
        }
        // A3. right boundary state for lane63 of each wave (LDS / halo).
        float wr0, wr1, wr2, wr3, wr4;
        if (lane == 63) {
            if (tid == ABLK - 1) {
                if (lb < ANBLK - 1) {
                    while (devloadu(&brow[lb + 1]) & 0x80000000u)
                        __builtin_amdgcn_s_sleep(1);
                    const float* h = halo + ((size_t)k * ANBLK + (lb + 1)) * 6;
                    wr0 = devloadf(h); wr1 = devloadf(h+1); wr2 = devloadf(h+2);
                    float E5 = wr2 * IGM1 + 0.5f * wr0 * wr1 * wr1;
                    float q5 = frsq(wr0);
                    wr3 = wr0 * q5; wr4 = (E5 + wr2) * q5;
                } else {
                    wr0 = cr[3]; wr1 = cu[3]; wr2 = cp[3];
                    wr3 = cs[3]; wr4 = cg[3];
                }
            } else {
                const float* w = R0[kb][wid + 1];
                wr0 = w[0]; wr1 = w[1]; wr2 = w[2]; wr3 = w[3]; wr4 = w[4];
            }
        }

        // B. left state via shfl_up (s,g travel with the state); interior
        //    fluxes first for ILP under ds/global load latency.
        float rl = __shfl_up(cr[3], 1), ul = __shfl_up(cu[3], 1);
        float pl = __shfl_up(cp[3], 1);
        float sl = __shfl_up(cs[3], 1), gl = __shfl_up(cg[3], 1);
        if (lane == 0) { rl = wl0; ul = wl1; pl = wl2; sl = wl3; gl = wl4; }

        roe(cr[0],cu[0],cp[0],cs[0],cg[0], cr[1],cu[1],cp[1],cs[1],cg[1],
            Fr[1], Fm[1], Fe[1]);
        roe(cr[1],cu[1],cp[1],cs[1],cg[1], cr[2],cu[2],cp[2],cs[2],cg[2],
            Fr[2], Fm[2], Fe[2]);
        roe(cr[2],cu[2],cp[2],cs[2],cg[2], cr[3],cu[3],cp[3],cs[3],cg[3],
            Fr[3], Fm[3], Fe[3]);
        roe(rl,ul,pl,sl,gl, cr[0],cu[0],cp[0],cs[0],cg[0],
            Fr[0], Fm[0], Fe[0]);

        // flux4 = next lane's flux0 (bit-identical move); lane63 recomputes
        // from the neighbor wave's stored state (identical inputs =>
        // identical flux, so wave seams add no numeric diffs).
        Fr[4] = __shfl_down(Fr[0], 1);
        Fm[4] = __shfl_down(Fm[0], 1);
        Fe[4] = __shfl_down(Fe[0], 1);
        if (lane == 63) {
            roe(cr[3],cu[3],cp[3],cs[3],cg[3], wr0,wr1,wr2,wr3,wr4,
                Fr[4], Fm[4], Fe[4]);
        }

        // C. dt for THIS step: k=0 one-time all-wave poll of row 0 (also
        //    produces sam[1]: dt_1 = f(row 0), r19 schedule); k>=1 read
        //    the parity-pipelined LDS broadcast (written during step k-1).
        float m;
        if (k == 0) {
            unsigned q0 = devloadu(&brow[lane]);
            unsigned q1 = devloadu(&brow[64 + lane]);
            unsigned q2 = devloadu(&brow[128 + lane]);
            unsigned q3 = devloadu(&brow[192 + lane]);
            while (!__all(((q0 | q1 | q2 | q3) & 0x80000000u) == 0u)) {
                __builtin_amdgcn_s_sleep(1);
                q0 = devloadu(&brow[lane]);
                q1 = devloadu(&brow[64 + lane]);
                q2 = devloadu(&brow[128 + lane]);
                q3 = devloadu(&brow[192 + lane]);
            }
            m = fmaxf(fmaxf(__uint_as_float(q0), __uint_as_float(q1)),
                      fmaxf(__uint_as_float(q2), __uint_as_float(q3)));
            m = wave_max(m);
            if (tid == 0) sam[1] = m;
        } else {
            m = sam[kb];
        }
        float dt = fminf((CFLC * DXC) * frcp(m), fmaxf(tfin - t, 0.f));
        t += dt;
        float dtdx = dt * IDXC;

        // D. update + carry refresh
        float nm = 0.f;
        #pragma unroll
        for (int c = 0; c < 4; ++c) {
            float r2 = cr[c]         - dtdx * (Fr[c+1] - Fr[c]);
            float m2 = cr[c] * cu[c] - dtdx * (Fm[c+1] - Fm[c]);
            float E2 = cE[c]         - dtdx * (Fe[c+1] - Fe[c]);
            float q2 = frsq(r2);
            float ir = q2 * q2;
            float u2 = m2 * ir;
            float p2 = GM1 * (E2 - 0.5f * r2 * u2 * u2);
            cr[c]=r2; cu[c]=u2; cp[c]=p2; cE[c]=E2;
            cs[c]=r2 * q2;                 // bit-identical to recompute
            cg[c]=(E2 + p2) * q2;          // conservative E2, as in ref
            nm = fmaxf(nm, fabsf(u2) + fsqrt_(GAM * p2 * ir));
        }

        if (k < NSTEPS - 1) {
            const int nb = (k + 1) & 1;
            // E. wave0: consume the pre-issued row-k poll -> sam[nb]
            //    (before the barrier; read by all waves at step k+1).
            if (w0poll) {
                while (!__all(((pv0 | pv1 | pv2 | pv3) & 0x80000000u) == 0u)) {
                    __builtin_amdgcn_s_sleep(1);
                    pv0 = devloadu(&brow[lane]);
                    pv1 = devloadu(&brow[64 + lane]);
                    pv2 = devloadu(&brow[128 + lane]);
                    pv3 = devloadu(&brow[192 + lane]);
                }
                float mn = fmaxf(fmaxf(__uint_as_float(pv0), __uint_as_float(pv1)),
                                 fmaxf(__uint_as_float(pv2), __uint_as_float(pv3)));
                mn = wave_max(mn);
                if (lane == 0) sam[nb] = mn;
            }
            // end-of-step writes (all BEFORE the single barrier)
            if (lane == 63) {
                W3[nb][wid][0]=cr[3]; W3[nb][wid][1]=cu[3]; W3[nb][wid][2]=cp[3];
                W3[nb][wid][3]=cs[3]; W3[nb][wid][4]=cg[3];
            }
            if (lane == 0) {
                R0[nb][wid][0]=cr[0]; R0[nb][wid][1]=cu[0]; R0[nb][wid][2]=cp[0];
                R0[nb][wid][3]=cs[0]; R0[nb][wid][4]=cg[0];
            }
            if (tid == 0) {
                float* h = halo + ((size_t)(k + 1) * ANBLK + lb) * 6;
                devstoref(h, cr[0]); devstoref(h+1, cu[0]); devstoref(h+2, cp[0]);
            }
            if (tid == ABLK - 1) {
                float* h = halo + ((size_t)(k + 1) * ANBLK + lb) * 6 + 3;
                devstoref(h, cr[3]); devstoref(h+1, cu[3]); devstoref(h+2, cp[3]);
            }
            nm = wave_max(nm);
            if (lane == 0) red[nb][wid] = nm;
            __syncthreads();   // THE barrier: drains halo stores + LDS[nb]
            // publisher = wave 8 (wave0 owns the polls, wave15 tid1023's)
            if (wid == 8 && lane < NWAVE) {
                float bm = red[nb][lane];
                bm = fmaxf(bm, __shfl_xor(bm, 8));
                bm = fmaxf(bm, __shfl_xor(bm, 4));
                bm = fmaxf(bm, __shfl_xor(bm, 2));
                bm = fmaxf(bm, __shfl_xor(bm, 1));
                if (lane == 0)
                    devstoreu(&bmax[(size_t)(k + 1) * ANBLK + lb],
                              __float_as_uint(bm));          // sign clear
            }
        } else {
            *(float4*)(out + c0)         = make_float4(cr[0], cr[1], cr[2], cr[3]);
            *(float4*)(out + NXC + c0)   = make_float4(cu[0], cu[1], cu[2], cu[3]);
            *(float4*)(out + 2*NXC + c0) = make_float4(cp[0], cp[1], cp[2], cp[3]);
        }
    }
}

extern "C" void kernel_launch(void* const* d_in, const int* in_sizes, int n_in,
                              void* d_out, int out_size, void* d_ws, size_t ws_size,
                              hipStream_t stream) {
    const float* rho0 = (const float*)d_in[0];
    const float* u0   = (const float*)d_in[1];
    const float* p0   = (const float*)d_in[2];
    const float* tf   = (const float*)d_in[3];
    // d_in[4] = n_steps (fixed at 32)

    float* out      = (float*)d_out;
    unsigned* bmax  = (unsigned*)d_ws;                   // 33*256 uints
    float* halo     = (float*)(bmax + CTRL_TOTAL);       // 33*256*6 floats

    bmax_init<<<(CTRL_TOTAL + 255) / 256, 256, 0, stream>>>(bmax);

    // Unconditional cooperative launch (no host queries: they fail during
    // stream capture and silently swap the timed graph -- round-11 lesson).
    void* args[] = {(void*)&rho0, (void*)&u0, (void*)&p0, (void*)&tf,
                    (void*)&out, (void*)&bmax, (void*)&halo};
    hipLaunchCooperativeKernel((void*)euler_async, dim3(ANBLK), dim3(ABLK),
                               args, 0, stream);
}

// Round 8
// 241.169 us; speedup vs baseline: 1.7160x; 1.7160x over previous
//
#include <hip/hip_runtime.h>

// 1D Euler, Roe flux + Harten entropy fix, 32 fused steps. Round 22:
// r20/r21 (shfl-exchange + single barrier) both regressed hard (243/334us)
// with inflated FETCH/WRITE => the grid de-synchronized and polls stopped
// being first-try (~40 rounds/step by traffic arithmetic). Mechanism not
// fully isolated; methodology says revert to the proven skeleton.
// r22 = r19 byte-for-byte (verified 127us, absmax 0.0078125) + ONE graft:
// parity-pipelined sam[2]. In r19, barrier #1 is held hostage by wave0's
// poll-all(row k) -> wave_max -> samax chain (global coherence RT on every
// step's critical path). Since dt_k = f(row k-1) (r19's verified slack),
// the poll whose result is needed at step k+1 runs DURING step k and
// crosses the EXISTING barrier #2:
//  - phase A: wave0 issues row-k flag loads (row k published at end of
//    step k-1 -> a full step of slack by consume time);
//  - pre-barrier#2: wave0 consumes (first-try expected), reduces, writes
//    sam[(k+1)&1];
//  - phase C (after barrier #1): ALL waves read sam[k&1] -- LDS
//    broadcast, zero global traffic gating barrier #1.
//  - k=0: wave0 polls row 0 at the old phase-E spot, writes sam[0] AND
//    sam[1] (dt_1 = f(row 0), exactly r19's schedule).
// Parity slots are separated by >=2 barriers between write and any
// conflicting read -> race-free. dt values + reduction tree bit-identical
// to r19 => identical trajectory.

#define NXC   1048576
#define GAM   1.4f
#define GM1   0.4f
#define IGM1  2.5f
#define CFLC  0.5f
#define DXC   1e-3f
#define IDXC  1000.0f
#define EFIX  0.1f
#define NSTEPS 32
#define NSLOT  (NSTEPS + 1)

#define ABLK  1024
#define ACPT  4
#define ATILE (ABLK*ACPT)      // 4096
#define ANBLK (NXC/ATILE)      // 256 blocks = 1/CU (proven residency)

#define CTRL_TOTAL (NSLOT * ANBLK)

__device__ __forceinline__ float frcp(float x){ return __builtin_amdgcn_rcpf(x); }
__device__ __forceinline__ float frsq(float x){ return __builtin_amdgcn_rsqf(x); }
__device__ __forceinline__ float fsqrt_(float x){ return __builtin_amdgcn_sqrtf(x); }

// Device (agent) scope: cross-XCD correct, no system-level overhead.
__device__ __forceinline__ float devloadf(const float* p) {
    return __hip_atomic_load(p, __ATOMIC_RELAXED, __HIP_MEMORY_SCOPE_AGENT);
}
__device__ __forceinline__ void devstoref(float* p, float v) {
    __hip_atomic_store(p, v, __ATOMIC_RELAXED, __HIP_MEMORY_SCOPE_AGENT);
}
__device__ __forceinline__ unsigned devloadu(const unsigned* p) {
    return __hip_atomic_load(p, __ATOMIC_RELAXED, __HIP_MEMORY_SCOPE_AGENT);
}
__device__ __forceinline__ void devstoreu(unsigned* p, unsigned v) {
    __hip_atomic_store(p, v, __ATOMIC_RELAXED, __HIP_MEMORY_SCOPE_AGENT);
}

__device__ __forceinline__ float wave_max(float v) {
    #pragma unroll
    for (int k = 32; k >= 1; k >>= 1)
        v = fmaxf(v, __shfl_xor(v, k));
    return v;
}

// Sign-SET sentinel = "unpublished" (deterministic regardless of ws poison).
__global__ void bmax_init(unsigned* z) {
    int i = blockIdx.x * 256 + threadIdx.x;
    if (i < CTRL_TOTAL) z[i] = 0xAAAAAAAAu;
}

// One Roe flux from scalar L/R states (s = sqrt(rho), g = (E+p)/sqrt(rho)).
__device__ __forceinline__ void roe(
        float rL, float uL, float pL, float sL, float gL,
        float rR, float uR, float pR, float sR, float gR,
        float& Frj, float& Fmj, float& Fej) {
    float invden = frcp(sL + sR);
    float ur = (sL * uL + sR * uR) * invden;
    float Hr = (gL + gR) * invden;
    float c2u = fmaxf(GM1 * (Hr - 0.5f * ur * ur), 1e-10f);
    float qc = frsq(c2u);
    float c  = c2u * qc;             // sqrt(c2u), ~1 ulp vs v_sqrt
    float inv2c2 = 0.5f * qc * qc;   // 1/(2*c2), replaces v_rcp
    float eps = EFIX * c;
    float l1 = ur - c, l3 = ur + c;
    float a1 = fsqrt_(l1 * l1 + eps * eps);
    float a2 = fsqrt_(ur * ur + eps * eps);
    float a3 = fsqrt_(l3 * l3 + eps * eps);
    float drho = rR - rL;
    float du   = uR - uL;
    float dp   = pR - pL;
    float al2 = drho - (dp + dp) * inv2c2;
    float tcd = c * rR * du;
    float al1 = (dp - tcd) * inv2c2;
    float al3 = (dp + tcd) * inv2c2;
    float FrL = rL * uL, FrR = rR * uR;
    float FmL = FrL * uL + pL, FmR = FrR * uR + pR;
    float FeL = uL * (gL * sL), FeR = uR * (gR * sR);
    float w1 = a1 * al1, w2 = a2 * al2, w3 = a3 * al3;
    Frj = 0.5f * (FrL + FrR - (w1 + w2 + w3));
    Fmj = 0.5f * (FmL + FmR - (w1 * l1 + w2 * ur + w3 * l3));
    Fej = 0.5f * (FeL + FeR - (w1 * (Hr - ur * c) + w2 * (0.5f * ur * ur)
                               + w3 * (Hr + ur * c)));
}

__global__ __launch_bounds__(ABLK, 4) void euler_async(
        const float* __restrict__ rho0, const float* __restrict__ u0,
        const float* __restrict__ p0, const float* __restrict__ tf,
        float* __restrict__ out, unsigned* __restrict__ bmax,
        float* __restrict__ halo) {   // halo: NSLOT rows x ANBLK x 6
    __shared__ float Lr[ABLK], Lu[ABLK], Lp[ABLK];    // each thread's cell3
    __shared__ float fxr[ABLK], fxm[ABLK], fxe[ABLK]; // each thread's flux0
    __shared__ float red[ABLK / 64];
    __shared__ float sam[2];          // global amax, parity-pipelined

    const int tid = threadIdx.x;
    // XCD swizzle (kept from r18: time-neutral, lowers L2 misses).
    const int lb = (blockIdx.x & 7) * (ANBLK / 8) + (blockIdx.x >> 3);
    const int c0 = lb * ATILE + ACPT * tid;
    const int lane = tid & 63, wid = tid >> 6;

    float cr[4], cu[4], cp[4], cE[4], cs[4], cg[4];

    // ---- prepass: inputs -> regs (incl E,s,g); publish halo+bmax row 0 --
    {
        float4 r4 = *(const float4*)(rho0 + c0);
        float4 u4 = *(const float4*)(u0 + c0);
        float4 p4 = *(const float4*)(p0 + c0);
        cr[0]=r4.x; cr[1]=r4.y; cr[2]=r4.z; cr[3]=r4.w;
        cu[0]=u4.x; cu[1]=u4.y; cu[2]=u4.z; cu[3]=u4.w;
        cp[0]=p4.x; cp[1]=p4.y; cp[2]=p4.z; cp[3]=p4.w;
        float nm = 0.f;
        #pragma unroll
        for (int c = 0; c < 4; ++c) {
            float E = cp[c] * IGM1 + 0.5f * cr[c] * cu[c] * cu[c];
            float q = frsq(cr[c]);
            cE[c] = E;
            cs[c] = cr[c] * q;
            cg[c] = (E + cp[c]) * q;
            nm = fmaxf(nm, fabsf(cu[c]) + fsqrt_(GAM * cp[c] * (q * q)));
        }
        Lr[tid]=cr[3]; Lu[tid]=cu[3]; Lp[tid]=cp[3];
        if (tid == 0) {
            float* h = halo + (size_t)lb * 6;
            devstoref(h, cr[0]); devstoref(h+1, cu[0]); devstoref(h+2, cp[0]);
        }
        if (tid == ABLK - 1) {
            float* h = halo + (size_t)lb * 6 + 3;
            devstoref(h, cr[3]); devstoref(h+1, cu[3]); devstoref(h+2, cp[3]);
        }
        nm = wave_max(nm);
        if (lane == 0) red[wid] = nm;
        __syncthreads();      // drains every wave's halo stores + red[]
        if (tid < ABLK / 64) {
            float bm = red[tid];
            bm = fmaxf(bm, __shfl_xor(bm, 8));
            bm = fmaxf(bm, __shfl_xor(bm, 4));
            bm = fmaxf(bm, __shfl_xor(bm, 2));
            bm = fmaxf(bm, __shfl_xor(bm, 1));
            if (tid == 0) devstoreu(&bmax[lb], __float_as_uint(bm)); // sign clear
        }
    }
    float t = 0.f;
    const float tfin = *tf;

    for (int k = 0; k < NSTEPS; ++k) {
        const unsigned* brow = bmax + (size_t)k * ANBLK;  // row k flags
        const int kb = k & 1;
        float Fr[5], Fm[5], Fe[5];

        // A0. wave0 (1<=k<=30): issue row-k flag loads for step k+1's dt.
        //     Row k was published at end of step k-1 -> a full step of
        //     slack before the pre-barrier-#2 consume.
        const bool w0poll = (wid == 0) && (k >= 1) && (k < NSTEPS - 1);
        unsigned pv0 = 0, pv1 = 0, pv2 = 0, pv3 = 0;
        if (w0poll) {
            pv0 = devloadu(&brow[lane]);
            pv1 = devloadu(&brow[64 + lane]);
            pv2 = devloadu(&brow[128 + lane]);
            pv3 = devloadu(&brow[192 + lane]);
        }

        // A. edge polls (neighbor flag only -- publishes early) + halo
        //    reads ISSUED at step top; consumed after the interior fluxes.
        float rl, ul, pl;
        float r5 = 0.f, u5 = 0.f, p5 = 0.f;
        if (tid == 0) {
            if (lb > 0) {
                while (devloadu(&brow[lb - 1]) & 0x80000000u)
                    __builtin_amdgcn_s_sleep(1);
                const float* h = halo + ((size_t)k * ANBLK + (lb - 1)) * 6 + 3;
                rl = devloadf(h); ul = devloadf(h+1); pl = devloadf(h+2);
            } else { rl = cr[0]; ul = cu[0]; pl = cp[0]; }
        } else { rl = Lr[tid-1]; ul = Lu[tid-1]; pl = Lp[tid-1]; }
        if (tid == ABLK - 1) {
            if (lb < ANBLK - 1) {
                while (devloadu(&brow[lb + 1]) & 0x80000000u)
                    __builtin_amdgcn_s_sleep(1);
                const float* h = halo + ((size_t)k * ANBLK + (lb + 1)) * 6;
                r5 = devloadf(h); u5 = devloadf(h+1); p5 = devloadf(h+2);
            } else { r5 = cr[3]; u5 = cu[3]; p5 = cp[3]; }
        }

        // B. interior fluxes (register inputs only) -- hide A's load latency.
        roe(cr[0],cu[0],cp[0],cs[0],cg[0], cr[1],cu[1],cp[1],cs[1],cg[1],
            Fr[1], Fm[1], Fe[1]);
        roe(cr[1],cu[1],cp[1],cs[1],cg[1], cr[2],cu[2],cp[2],cs[2],cg[2],
            Fr[2], Fm[2], Fe[2]);
        roe(cr[2],cu[2],cp[2],cs[2],cg[2], cr[3],cu[3],cp[3],cs[3],cg[3],
            Fr[3], Fm[3], Fe[3]);

        // C. left cell s,g + flux0 -> exchange LDS
        {
            float El = pl * IGM1 + 0.5f * rl * ul * ul;
            float ql = frsq(rl);
            float sl = rl * ql, gl = (El + pl) * ql;
            roe(rl,ul,pl,sl,gl, cr[0],cu[0],cp[0],cs[0],cg[0],
                Fr[0], Fm[0], Fe[0]);
            fxr[tid] = Fr[0]; fxm[tid] = Fm[0]; fxe[tid] = Fe[0];
        }

        // D. right edge only: flux4 (halo read issued in A)
        if (tid == ABLK - 1) {
            float E5 = p5 * IGM1 + 0.5f * r5 * u5 * u5;
            float q5 = frsq(r5);
            float s5 = r5 * q5, g5 = (E5 + p5) * q5;
            roe(cr[3],cu[3],cp[3],cs[3],cg[3], r5,u5,p5,s5,g5,
                Fr[4], Fm[4], Fe[4]);
        }

        // E0. k=0 only: wave0 polls row 0 (published in prepass) ->
        //     sam[0] for this step and sam[1] for step 1 (dt_1 = f(row 0),
        //     exactly r19's slack schedule).
        if (k == 0 && wid == 0) {
            unsigned q0, q1, q2, q3;
            for (;;) {
                q0 = devloadu(&brow[lane]);
                q1 = devloadu(&brow[64 + lane]);
                q2 = devloadu(&brow[128 + lane]);
                q3 = devloadu(&brow[192 + lane]);
                if (__all(((q0 | q1 | q2 | q3) & 0x80000000u) == 0u)) break;
                __builtin_amdgcn_s_sleep(1);
            }
            float m0 = fmaxf(fmaxf(__uint_as_float(q0), __uint_as_float(q1)),
                             fmaxf(__uint_as_float(q2), __uint_as_float(q3)));
            m0 = wave_max(m0);
            if (lane == 0) { sam[0] = m0; sam[1] = m0; }
        }

        __syncthreads();   // #1: sam (k=0) + flux LDS ready; Lr reads done

        if (tid < ABLK - 1) {
            Fr[4] = fxr[tid + 1]; Fm[4] = fxm[tid + 1]; Fe[4] = fxe[tid + 1];
        }
        float amax = sam[kb];     // LDS broadcast; no global traffic here
        float dt = fminf((CFLC * DXC) * frcp(amax), fmaxf(tfin - t, 0.f));
        t += dt;
        float dtdx = dt * IDXC;

        float nm = 0.f;
        #pragma unroll
        for (int c = 0; c < 4; ++c) {
            float r2 = cr[c]         - dtdx * (Fr[c+1] - Fr[c]);
            float m2 = cr[c] * cu[c] - dtdx * (Fm[c+1] - Fm[c]);
            float E2 = cE[c]         - dtdx * (Fe[c+1] - Fe[c]);
            float q2 = frsq(r2);
            float ir = q2 * q2;
            float u2 = m2 * ir;
            float p2 = GM1 * (E2 - 0.5f * r2 * u2 * u2);
            cr[c]=r2; cu[c]=u2; cp[c]=p2; cE[c]=E2;
            cs[c]=r2 * q2;                 // bit-identical to recompute
            cg[c]=(E2 + p2) * q2;          // conservative E2, as in ref
            nm = fmaxf(nm, fabsf(u2) + fsqrt_(GAM * p2 * ir));
        }

        if (k < NSTEPS - 1) {
            Lr[tid]=cr[3]; Lu[tid]=cu[3]; Lp[tid]=cp[3];
            if (tid == 0) {
                float* h = halo + ((size_t)(k + 1) * ANBLK + lb) * 6;
                devstoref(h, cr[0]); devstoref(h+1, cu[0]); devstoref(h+2, cp[0]);
            }
            if (tid == ABLK - 1) {
                float* h = halo + ((size_t)(k + 1) * ANBLK + lb) * 6 + 3;
                devstoref(h, cr[3]); devstoref(h+1, cu[3]); devstoref(h+2, cp[3]);
            }
            // E. wave0: consume the pre-issued row-k poll -> sam[(k+1)&1]
            //    (written BEFORE barrier #2; read at step k+1 after its
            //    barrier #1 -> separated by two barriers, race-free).
            if (w0poll) {
                while (!__all(((pv0 | pv1 | pv2 | pv3) & 0x80000000u) == 0u)) {
                    __builtin_amdgcn_s_sleep(1);
                    pv0 = devloadu(&brow[lane]);
                    pv1 = devloadu(&brow[64 + lane]);
                    pv2 = devloadu(&brow[128 + lane]);
                    pv3 = devloadu(&brow[192 + lane]);
                }
                float mn = fmaxf(fmaxf(__uint_as_float(pv0), __uint_as_float(pv1)),
                                 fmaxf(__uint_as_float(pv2), __uint_as_float(pv3)));
                mn = wave_max(mn);
                if (lane == 0) sam[(k + 1) & 1] = mn;
            }
            nm = wave_max(nm);
            if (lane == 0) red[wid] = nm;
            __syncthreads();   // #2: drains halo stores; LDS ready for k+1
            if (tid < ABLK / 64) {
                float bm = red[tid];
                bm = fmaxf(bm, __shfl_xor(bm, 8));
                bm = fmaxf(bm, __shfl_xor(bm, 4));
                bm = fmaxf(bm, __shfl_xor(bm, 2));
                bm = fmaxf(bm, __shfl_xor(bm, 1));
                if (tid == 0)
                    devstoreu(&bmax[(size_t)(k + 1) * ANBLK + lb],
                              __float_as_uint(bm));          // sign clear
            }
        } else {
            *(float4*)(out + c0)         = make_float4(cr[0], cr[1], cr[2], cr[3]);
            *(float4*)(out + NXC + c0)   = make_float4(cu[0], cu[1], cu[2], cu[3]);
            *(float4*)(out + 2*NXC + c0) = make_float4(cp[0], cp[1], cp[2], cp[3]);
        }
    }
}

extern "C" void kernel_launch(void* const* d_in, const int* in_sizes, int n_in,
                              void* d_out, int out_size, void* d_ws, size_t ws_size,
                              hipStream_t stream) {
    const float* rho0 = (const float*)d_in[0];
    const float* u0   = (const float*)d_in[1];
    const float* p0   = (const float*)d_in[2];
    const float* tf   = (const float*)d_in[3];
    // d_in[4] = n_steps (fixed at 32)

    float* out      = (float*)d_out;
    unsigned* bmax  = (unsigned*)d_ws;                   // 33*256 uints
    float* halo     = (float*)(bmax + CTRL_TOTAL);       // 33*256*6 floats

    bmax_init<<<(CTRL_TOTAL + 255) / 256, 256, 0, stream>>>(bmax);

    // Unconditional cooperative launch (no host queries: they fail during
    // stream capture and silently swap the timed graph -- round-11 lesson).
    void* args[] = {(void*)&rho0, (void*)&u0, (void*)&p0, (void*)&tf,
                    (void*)&out, (void*)&bmax, (void*)&halo};
    hipLaunchCooperativeKernel((void*)euler_async, dim3(ANBLK), dim3(ABLK),
                               args, 0, stream);
}

// Round 9
// 201.488 us; speedup vs baseline: 2.0540x; 1.1969x over previous
//
#include <hip/hip_runtime.h>

// 1D Euler, Roe flux + Harten entropy fix, 32 fused steps. Round 23:
// r20-r22 established that the r19 sync structure is the optimum of its
// family (r16/r18/r19 = 127us; every deviation regressed: r17 launch-fail,
// r20 243us per-wave-poll traffic, r21 334us de-sync, r22 163us poll RT
// serialized into the publish chain). r23 keeps r19 BYTE-FOR-BYTE in all
// sync/exchange/protocol and attacks the other half of the step: the
// ~2.7us/step VALU-busy term, which is issue-bound SCALAR fp32.
// gfx950 dual-issues packed fp32 (v_pk_fma/add/mul_f32, the 157TF vector
// peak); hipcc emits them for ext_vector_type(2) arithmetic only. The
// flux math is 4 independent interfaces + 4 independent cells per thread:
//  - roe2: two interfaces per call on float2 ext-vectors. Pair1=(I1,I2)
//    register-only (keeps r19's hide-the-halo-latency role); pair2=
//    (I3,I0) consumes the left state. Same op sequence as scalar roe.
//  - update: cells (0,1) and (2,3) as two float2 packs.
//  - transcendentals stay scalar per component (no packed rsq/sqrt);
//    count unchanged. Plain mul/add/fma (~250/thread/step) halve their
//    issue slots.
// Numerics: packed ops are IEEE-identical to scalar; only fma-contraction
// choices can differ (same 1-ulp class as accepted prior variants).

#define NXC   1048576
#define GAM   1.4f
#define GM1   0.4f
#define IGM1  2.5f
#define CFLC  0.5f
#define DXC   1e-3f
#define IDXC  1000.0f
#define EFIX  0.1f
#define NSTEPS 32
#define NSLOT  (NSTEPS + 1)

#define ABLK  1024
#define ACPT  4
#define ATILE (ABLK*ACPT)      // 4096
#define ANBLK (NXC/ATILE)      // 256 blocks = 1/CU (proven residency)

#define CTRL_TOTAL (NSLOT * ANBLK)

typedef float f2 __attribute__((ext_vector_type(2)));

__device__ __forceinline__ float frcp(float x){ return __builtin_amdgcn_rcpf(x); }
__device__ __forceinline__ float frsq(float x){ return __builtin_amdgcn_rsqf(x); }
__device__ __forceinline__ float fsqrt_(float x){ return __builtin_amdgcn_sqrtf(x); }

__device__ __forceinline__ f2 mkf2(float a, float b){ f2 v; v.x=a; v.y=b; return v; }
__device__ __forceinline__ f2 f2rcp(f2 a){ return mkf2(frcp(a.x), frcp(a.y)); }
__device__ __forceinline__ f2 f2rsq(f2 a){ return mkf2(frsq(a.x), frsq(a.y)); }
__device__ __forceinline__ f2 f2sqrt(f2 a){ return mkf2(fsqrt_(a.x), fsqrt_(a.y)); }
__device__ __forceinline__ f2 f2max(f2 a, f2 b){
    return mkf2(fmaxf(a.x,b.x), fmaxf(a.y,b.y));
}
__device__ __forceinline__ f2 f2abs(f2 a){
    return mkf2(fabsf(a.x), fabsf(a.y));
}

// Device (agent) scope: cross-XCD correct, no system-level overhead.
__device__ __forceinline__ float devloadf(const float* p) {
    return __hip_atomic_load(p, __ATOMIC_RELAXED, __HIP_MEMORY_SCOPE_AGENT);
}
__device__ __forceinline__ void devstoref(float* p, float v) {
    __hip_atomic_store(p, v, __ATOMIC_RELAXED, __HIP_MEMORY_SCOPE_AGENT);
}
__device__ __forceinline__ unsigned devloadu(const unsigned* p) {
    return __hip_atomic_load(p, __ATOMIC_RELAXED, __HIP_MEMORY_SCOPE_AGENT);
}
__device__ __forceinline__ void devstoreu(unsigned* p, unsigned v) {
    __hip_atomic_store(p, v, __ATOMIC_RELAXED, __HIP_MEMORY_SCOPE_AGENT);
}

__device__ __forceinline__ float wave_max(float v) {
    #pragma unroll
    for (int k = 32; k >= 1; k >>= 1)
        v = fmaxf(v, __shfl_xor(v, k));
    return v;
}

// Sign-SET sentinel = "unpublished" (deterministic regardless of ws poison).
__global__ void bmax_init(unsigned* z) {
    int i = blockIdx.x * 256 + threadIdx.x;
    if (i < CTRL_TOTAL) z[i] = 0xAAAAAAAAu;
}

// Scalar Roe flux (edge-interface only; one call per step per edge thread).
__device__ __forceinline__ void roe(
        float rL, float uL, float pL, float sL, float gL,
        float rR, float uR, float pR, float sR, float gR,
        float& Frj, float& Fmj, float& Fej) {
    float invden = frcp(sL + sR);
    float ur = (sL * uL + sR * uR) * invden;
    float Hr = (gL + gR) * invden;
    float c2u = fmaxf(GM1 * (Hr - 0.5f * ur * ur), 1e-10f);
    float qc = frsq(c2u);
    float c  = c2u * qc;
    float inv2c2 = 0.5f * qc * qc;
    float eps = EFIX * c;
    float l1 = ur - c, l3 = ur + c;
    float a1 = fsqrt_(l1 * l1 + eps * eps);
    float a2 = fsqrt_(ur * ur + eps * eps);
    float a3 = fsqrt_(l3 * l3 + eps * eps);
    float drho = rR - rL;
    float du   = uR - uL;
    float dp   = pR - pL;
    float al2 = drho - (dp + dp) * inv2c2;
    float tcd = c * rR * du;
    float al1 = (dp - tcd) * inv2c2;
    float al3 = (dp + tcd) * inv2c2;
    float FrL = rL * uL, FrR = rR * uR;
    float FmL = FrL * uL + pL, FmR = FrR * uR + pR;
    float FeL = uL * (gL * sL), FeR = uR * (gR * sR);
    float w1 = a1 * al1, w2 = a2 * al2, w3 = a3 * al3;
    Frj = 0.5f * (FrL + FrR - (w1 + w2 + w3));
    Fmj = 0.5f * (FmL + FmR - (w1 * l1 + w2 * ur + w3 * l3));
    Fej = 0.5f * (FeL + FeR - (w1 * (Hr - ur * c) + w2 * (0.5f * ur * ur)
                               + w3 * (Hr + ur * c)));
}

// Packed Roe flux: two independent interfaces per call (v_pk_* fp32 path).
__device__ __forceinline__ void roe2(
        f2 rL, f2 uL, f2 pL, f2 sL, f2 gL,
        f2 rR, f2 uR, f2 pR, f2 sR, f2 gR,
        f2& Frj, f2& Fmj, f2& Fej) {
    f2 invden = f2rcp(sL + sR);
    f2 ur = (sL * uL + sR * uR) * invden;
    f2 Hr = (gL + gR) * invden;
    f2 c2u = f2max(GM1 * (Hr - 0.5f * ur * ur), mkf2(1e-10f, 1e-10f));
    f2 qc = f2rsq(c2u);
    f2 c  = c2u * qc;
    f2 inv2c2 = 0.5f * qc * qc;
    f2 eps = EFIX * c;
    f2 l1 = ur - c, l3 = ur + c;
    f2 a1 = f2sqrt(l1 * l1 + eps * eps);
    f2 a2 = f2sqrt(ur * ur + eps * eps);
    f2 a3 = f2sqrt(l3 * l3 + eps * eps);
    f2 drho = rR - rL;
    f2 du   = uR - uL;
    f2 dp   = pR - pL;
    f2 al2 = drho - (dp + dp) * inv2c2;
    f2 tcd = c * rR * du;
    f2 al1 = (dp - tcd) * inv2c2;
    f2 al3 = (dp + tcd) * inv2c2;
    f2 FrL = rL * uL, FrR = rR * uR;
    f2 FmL = FrL * uL + pL, FmR = FrR * uR + pR;
    f2 FeL = uL * (gL * sL), FeR = uR * (gR * sR);
    f2 w1 = a1 * al1, w2 = a2 * al2, w3 = a3 * al3;
    Frj = 0.5f * (FrL + FrR - (w1 + w2 + w3));
    Fmj = 0.5f * (FmL + FmR - (w1 * l1 + w2 * ur + w3 * l3));
    Fej = 0.5f * (FeL + FeR - (w1 * (Hr - ur * c) + w2 * (0.5f * ur * ur)
                               + w3 * (Hr + ur * c)));
}

__global__ __launch_bounds__(ABLK, 4) void euler_async(
        const float* __restrict__ rho0, const float* __restrict__ u0,
        const float* __restrict__ p0, const float* __restrict__ tf,
        float* __restrict__ out, unsigned* __restrict__ bmax,
        float* __restrict__ halo) {   // halo: NSLOT rows x ANBLK x 6
    __shared__ float Lr[ABLK], Lu[ABLK], Lp[ABLK];    // each thread's cell3
    __shared__ float fxr[ABLK], fxm[ABLK], fxe[ABLK]; // each thread's flux0
    __shared__ float red[ABLK / 64];
    __shared__ float samax;

    const int tid = threadIdx.x;
    // XCD swizzle (kept from r18: time-neutral, lowers L2 misses).
    const int lb = (blockIdx.x & 7) * (ANBLK / 8) + (blockIdx.x >> 3);
    const int c0 = lb * ATILE + ACPT * tid;
    const int lane = tid & 63, wid = tid >> 6;

    float cr[4], cu[4], cp[4], cE[4], cs[4], cg[4];

    // ---- prepass: inputs -> regs (incl E,s,g); publish halo+bmax row 0 --
    {
        float4 r4 = *(const float4*)(rho0 + c0);
        float4 u4 = *(const float4*)(u0 + c0);
        float4 p4 = *(const float4*)(p0 + c0);
        cr[0]=r4.x; cr[1]=r4.y; cr[2]=r4.z; cr[3]=r4.w;
        cu[0]=u4.x; cu[1]=u4.y; cu[2]=u4.z; cu[3]=u4.w;
        cp[0]=p4.x; cp[1]=p4.y; cp[2]=p4.z; cp[3]=p4.w;
        float nm = 0.f;
        #pragma unroll
        for (int c = 0; c < 4; ++c) {
            float E = cp[c] * IGM1 + 0.5f * cr[c] * cu[c] * cu[c];
            float q = frsq(cr[c]);
            cE[c] = E;
            cs[c] = cr[c] * q;
            cg[c] = (E + cp[c]) * q;
            nm = fmaxf(nm, fabsf(cu[c]) + fsqrt_(GAM * cp[c] * (q * q)));
        }
        Lr[tid]=cr[3]; Lu[tid]=cu[3]; Lp[tid]=cp[3];
        if (tid == 0) {
            float* h = halo + (size_t)lb * 6;
            devstoref(h, cr[0]); devstoref(h+1, cu[0]); devstoref(h+2, cp[0]);
        }
        if (tid == ABLK - 1) {
            float* h = halo + (size_t)lb * 6 + 3;
            devstoref(h, cr[3]); devstoref(h+1, cu[3]); devstoref(h+2, cp[3]);
        }
        nm = wave_max(nm);
        if (lane == 0) red[wid] = nm;
        __syncthreads();      // drains every wave's halo stores + red[]
        if (tid < ABLK / 64) {
            float bm = red[tid];
            bm = fmaxf(bm, __shfl_xor(bm, 8));
            bm = fmaxf(bm, __shfl_xor(bm, 4));
            bm = fmaxf(bm, __shfl_xor(bm, 2));
            bm = fmaxf(bm, __shfl_xor(bm, 1));
            if (tid == 0) devstoreu(&bmax[lb], __float_as_uint(bm)); // sign clear
        }
    }
    float t = 0.f;
    const float tfin = *tf;

    for (int k = 0; k < NSTEPS; ++k) {
        const unsigned* brow = bmax + (size_t)k * ANBLK;  // halo gate (exact)
        // dt gate with one full step of slack (r19 semantics, verified).
        const unsigned* brdt = bmax + (size_t)(k > 0 ? k - 1 : 0) * ANBLK;
        float Fr[5], Fm[5], Fe[5];

        // A. edge polls (neighbor flag only -- publishes early) + halo
        //    reads ISSUED at step top; consumed after pair1.
        float rl, ul, pl;
        float r5 = 0.f, u5 = 0.f, p5 = 0.f;
        if (tid == 0) {
            if (lb > 0) {
                while (devloadu(&brow[lb - 1]) & 0x80000000u)
                    __builtin_amdgcn_s_sleep(1);
                const float* h = halo + ((size_t)k * ANBLK + (lb - 1)) * 6 + 3;
                rl = devloadf(h); ul = devloadf(h+1); pl = devloadf(h+2);
            } else { rl = cr[0]; ul = cu[0]; pl = cp[0]; }
        } else { rl = Lr[tid-1]; ul = Lu[tid-1]; pl = Lp[tid-1]; }
        if (tid == ABLK - 1) {
            if (lb < ANBLK - 1) {
                while (devloadu(&brow[lb + 1]) & 0x80000000u)
                    __builtin_amdgcn_s_sleep(1);
                const float* h = halo + ((size_t)k * ANBLK + (lb + 1)) * 6;
                r5 = devloadf(h); u5 = devloadf(h+1); p5 = devloadf(h+2);
            } else { r5 = cr[3]; u5 = cu[3]; p5 = cp[3]; }
        }

        // B. pair1 = interfaces (I1: c0|c1, I2: c1|c2), register-only --
        //    hides A's load latency, now on the packed fp32 pipe.
        f2 Fr12, Fm12, Fe12;
        roe2(mkf2(cr[0],cr[1]), mkf2(cu[0],cu[1]), mkf2(cp[0],cp[1]),
             mkf2(cs[0],cs[1]), mkf2(cg[0],cg[1]),
             mkf2(cr[1],cr[2]), mkf2(cu[1],cu[2]), mkf2(cp[1],cp[2]),
             mkf2(cs[1],cs[2]), mkf2(cg[1],cg[2]),
             Fr12, Fm12, Fe12);
        Fr[1] = Fr12.x; Fm[1] = Fm12.x; Fe[1] = Fe12.x;
        Fr[2] = Fr12.y; Fm[2] = Fm12.y; Fe[2] = Fe12.y;

        // C. left cell s,g; pair2 = (I3: c2|c3, I0: left|c0); flux0 -> LDS
        {
            float El = pl * IGM1 + 0.5f * rl * ul * ul;
            float ql = frsq(rl);
            float sl = rl * ql, gl = (El + pl) * ql;
            f2 Fr30, Fm30, Fe30;
            roe2(mkf2(cr[2], rl), mkf2(cu[2], ul), mkf2(cp[2], pl),
                 mkf2(cs[2], sl), mkf2(cg[2], gl),
                 mkf2(cr[3], cr[0]), mkf2(cu[3], cu[0]), mkf2(cp[3], cp[0]),
                 mkf2(cs[3], cs[0]), mkf2(cg[3], cg[0]),
                 Fr30, Fm30, Fe30);
            Fr[3] = Fr30.x; Fm[3] = Fm30.x; Fe[3] = Fe30.x;
            Fr[0] = Fr30.y; Fm[0] = Fm30.y; Fe[0] = Fe30.y;
            fxr[tid] = Fr[0]; fxm[tid] = Fm[0]; fxe[tid] = Fe[0];
        }

        // D. right edge only: flux4 (halo read issued in A), scalar.
        if (tid == ABLK - 1) {
            float E5 = p5 * IGM1 + 0.5f * r5 * u5 * u5;
            float q5 = frsq(r5);
            float s5 = r5 * q5, g5 = (E5 + p5) * q5;
            roe(cr[3],cu[3],cp[3],cs[3],cg[3], r5,u5,p5,s5,g5,
                Fr[4], Fm[4], Fe[4]);
        }

        // E. wave0: dt poll over the slack row (first-try in steady state)
        if (wid == 0) {
            unsigned v0, v1, v2, v3;
            for (;;) {
                v0 = devloadu(&brdt[lane]);
                v1 = devloadu(&brdt[64 + lane]);
                v2 = devloadu(&brdt[128 + lane]);
                v3 = devloadu(&brdt[192 + lane]);
                if (__all(((v0 | v1 | v2 | v3) & 0x80000000u) == 0u)) break;
                __builtin_amdgcn_s_sleep(1);
            }
            float m = fmaxf(fmaxf(__uint_as_float(v0), __uint_as_float(v1)),
                            fmaxf(__uint_as_float(v2), __uint_as_float(v3)));
            m = wave_max(m);
            if (lane == 0) samax = m;
        }

        __syncthreads();   // #1: samax + flux LDS ready; Lr reads done

        if (tid < ABLK - 1) {
            Fr[4] = fxr[tid + 1]; Fm[4] = fxm[tid + 1]; Fe[4] = fxe[tid + 1];
        }
        float amax = samax;
        float dt = fminf((CFLC * DXC) * frcp(amax), fmaxf(tfin - t, 0.f));
        t += dt;
        float dtdx = dt * IDXC;

        // Update as two float2 packs: cells (0,1) and (2,3).
        f2 dtv = mkf2(dtdx, dtdx);
        f2 rA = mkf2(cr[0],cr[1]), uA = mkf2(cu[0],cu[1]), EA = mkf2(cE[0],cE[1]);
        f2 rB = mkf2(cr[2],cr[3]), uB = mkf2(cu[2],cu[3]), EB = mkf2(cE[2],cE[3]);
        f2 r2A = rA      - dtv * (mkf2(Fr[1],Fr[2]) - mkf2(Fr[0],Fr[1]));
        f2 m2A = rA * uA - dtv * (mkf2(Fm[1],Fm[2]) - mkf2(Fm[0],Fm[1]));
        f2 E2A = EA      - dtv * (mkf2(Fe[1],Fe[2]) - mkf2(Fe[0],Fe[1]));
        f2 r2B = rB      - dtv * (mkf2(Fr[3],Fr[4]) - mkf2(Fr[2],Fr[3]));
        f2 m2B = rB * uB - dtv * (mkf2(Fm[3],Fm[4]) - mkf2(Fm[2],Fm[3]));
        f2 E2B = EB      - dtv * (mkf2(Fe[3],Fe[4]) - mkf2(Fe[2],Fe[3]));
        f2 q2A = f2rsq(r2A), q2B = f2rsq(r2B);
        f2 irA = q2A * q2A,  irB = q2B * q2B;
        f2 u2A = m2A * irA,  u2B = m2B * irB;
        f2 p2A = GM1 * (E2A - 0.5f * r2A * u2A * u2A);
        f2 p2B = GM1 * (E2B - 0.5f * r2B * u2B * u2B);
        f2 nmA = f2abs(u2A) + f2sqrt(GAM * p2A * irA);
        f2 nmB = f2abs(u2B) + f2sqrt(GAM * p2B * irB);
        f2 sA = r2A * q2A, sB = r2B * q2B;
        f2 gA = (E2A + p2A) * q2A, gB = (E2B + p2B) * q2B;
        cr[0]=r2A.x; cr[1]=r2A.y; cr[2]=r2B.x; cr[3]=r2B.y;
        cu[0]=u2A.x; cu[1]=u2A.y; cu[2]=u2B.x; cu[3]=u2B.y;
        cp[0]=p2A.x; cp[1]=p2A.y; cp[2]=p2B.x; cp[3]=p2B.y;
        cE[0]=E2A.x; cE[1]=E2A.y; cE[2]=E2B.x; cE[3]=E2B.y;
        cs[0]=sA.x;  cs[1]=sA.y;  cs[2]=sB.x;  cs[3]=sB.y;
        cg[0]=gA.x;  cg[1]=gA.y;  cg[2]=gB.x;  cg[3]=gB.y;
        float nm = fmaxf(fmaxf(nmA.x, nmA.y), fmaxf(nmB.x, nmB.y));

        if (k < NSTEPS - 1) {
            Lr[tid]=cr[3]; Lu[tid]=cu[3]; Lp[tid]=cp[3];
            if (tid == 0) {
                float* h = halo + ((size_t)(k + 1) * ANBLK + lb) * 6;
                devstoref(h, cr[0]); devstoref(h+1, cu[0]); devstoref(h+2, cp[0]);
            }
            if (tid == ABLK - 1) {
                float* h = halo + ((size_t)(k + 1) * ANBLK + lb) * 6 + 3;
                devstoref(h, cr[3]); devstoref(h+1, cu[3]); devstoref(h+2, cp[3]);
            }
            nm = wave_max(nm);
            if (lane == 0) red[wid] = nm;
            __syncthreads();   // #2: drains halo stores; LDS ready for k+1
            if (tid < ABLK / 64) {
                float bm = red[tid];
                bm = fmaxf(bm, __shfl_xor(bm, 8));
                bm = fmaxf(bm, __shfl_xor(bm, 4));
                bm = fmaxf(bm, __shfl_xor(bm, 2));
                bm = fmaxf(bm, __shfl_xor(bm, 1));
                if (tid == 0)
                    devstoreu(&bmax[(size_t)(k + 1) * ANBLK + lb],
                              __float_as_uint(bm));          // sign clear
            }
        } else {
            *(float4*)(out + c0)         = make_float4(cr[0], cr[1], cr[2], cr[3]);
            *(float4*)(out + NXC + c0)   = make_float4(cu[0], cu[1], cu[2], cu[3]);
            *(float4*)(out + 2*NXC + c0) = make_float4(cp[0], cp[1], cp[2], cp[3]);
        }
    }
}

extern "C" void kernel_launch(void* const* d_in, const int* in_sizes, int n_in,
                              void* d_out, int out_size, void* d_ws, size_t ws_size,
                              hipStream_t stream) {
    const float* rho0 = (const float*)d_in[0];
    const float* u0   = (const float*)d_in[1];
    const float* p0   = (const float*)d_in[2];
    const float* tf   = (const float*)d_in[3];
    // d_in[4] = n_steps (fixed at 32)

    float* out      = (float*)d_out;
    unsigned* bmax  = (unsigned*)d_ws;                   // 33*256 uints
    float* halo     = (float*)(bmax + CTRL_TOTAL);       // 33*256*6 floats

    bmax_init<<<(CTRL_TOTAL + 255) / 256, 256, 0, stream>>>(bmax);

    // Unconditional cooperative launch (no host queries: they fail during
    // stream capture and silently swap the timed graph -- round-11 lesson).
    void* args[] = {(void*)&rho0, (void*)&u0, (void*)&p0, (void*)&tf,
                    (void*)&out, (void*)&bmax, (void*)&halo};
    hipLaunchCooperativeKernel((void*)euler_async, dim3(ANBLK), dim3(ABLK),
                               args, 0, stream);
}